// Round 12
// baseline (149.016 us; speedup 1.0000x reference)
//
#include <hip/hip_runtime.h>
#include <hip/hip_bf16.h>

#define B_ 2
#define T_ 2048
#define D_ 1024
#define H_ 16
#define M_ (B_ * T_)  // 4096 tokens

typedef __attribute__((ext_vector_type(4))) float f32x4;
typedef __attribute__((ext_vector_type(16))) float f32x16;
typedef __attribute__((ext_vector_type(8))) short s16x8;
typedef __attribute__((ext_vector_type(4))) short s16x4;
typedef __attribute__((ext_vector_type(4))) unsigned u32x4;

__device__ __forceinline__ short f2bs(float f) {
  unsigned u = __builtin_bit_cast(unsigned, f);
  u += 0x7fffu + ((u >> 16) & 1u);
  return (short)(u >> 16);
}
// v_cvt_pk_bf16_f32: dst.lo = bf16(lo), dst.hi = bf16(hi) (RTNE)
__device__ __forceinline__ unsigned cvt_pk_bf16(float lo, float hi) {
  unsigned r;
  asm("v_cvt_pk_bf16_f32 %0, %1, %2" : "=v"(r) : "v"(lo), "v"(hi));
  return r;
}

// ---------------- fp32 -> bf16 convert (x) ----------------
__global__ __launch_bounds__(256) void cvt_f32_bf16(const float* __restrict__ in,
                                                    short* __restrict__ out, int n4) {
  int i = blockIdx.x * 256 + threadIdx.x;
  if (i < n4) {
    float4 v = ((const float4*)in)[i];
    s16x4 o;
    o.x = f2bs(v.x); o.y = f2bs(v.y); o.z = f2bs(v.z); o.w = f2bs(v.w);
    ((s16x4*)out)[i] = o;
  }
}

// ---------------- fp32 W[k][n] -> bf16 Wt[n][k] (transpose) ----------------
__global__ __launch_bounds__(256) void cvt_transpose(
    const float* __restrict__ w0, const float* __restrict__ w1,
    const float* __restrict__ w2, const float* __restrict__ w3,
    short* __restrict__ o0, short* __restrict__ o1,
    short* __restrict__ o2, short* __restrict__ o3) {
  __shared__ float tile[64][65];
  const float* W; short* Wt;
  if (blockIdx.z == 0) { W = w0; Wt = o0; }
  else if (blockIdx.z == 1) { W = w1; Wt = o1; }
  else if (blockIdx.z == 2) { W = w2; Wt = o2; }
  else { W = w3; Wt = o3; }
  const int k0 = blockIdx.x * 64, n0 = blockIdx.y * 64;
  const int t = threadIdx.x;
  const int c = t & 63, r4 = t >> 6;
#pragma unroll
  for (int i = 0; i < 16; ++i) {
    int row = i * 4 + r4;
    tile[row][c] = W[(size_t)(k0 + row) * D_ + n0 + c];
  }
  __syncthreads();
#pragma unroll
  for (int i = 0; i < 16; ++i) {
    int row = i * 4 + r4;
    Wt[(size_t)(n0 + row) * D_ + k0 + c] = f2bs(tile[c][row]);
  }
}

// ---------------- 128x128 bf16 MFMA GEMM core (BK=64, Wt pre-transposed) ----
// r7-green version (best measured). XCD-chunked block swizzle.
template <int MODE>
__device__ __forceinline__ void gemm_core(short As[128][72], short Bs[128][72],
                                          const short* __restrict__ A,
                                          const short* __restrict__ Wt,
                                          const float* __restrict__ bias,
                                          const float* __restrict__ resid,
                                          void* __restrict__ outp, float mult) {
  const int t = threadIdx.x;
  const int lane = t & 63, wid = t >> 6;
  const int l15 = lane & 15, g = lane >> 4;
  const int wr = wid >> 1, wc = wid & 1;
  const int f = blockIdx.y * 8 + blockIdx.x;       // [0,256)
  const int nf = (f & 7) * 32 + (f >> 3);          // bijective remap
  const int n0 = (nf & 7) * 128;
  const int m0 = (nf >> 3) * 128;

  const f32x4 fz = {0.f, 0.f, 0.f, 0.f};
  f32x4 acc[4][4];
#pragma unroll
  for (int m = 0; m < 4; ++m)
#pragma unroll
    for (int n = 0; n < 4; ++n) acc[m][n] = fz;

  const int srow = t >> 1, shalf = (t & 1) * 32;
  const short* ap = A + (size_t)(m0 + srow) * D_ + shalf;
  const short* bp = Wt + (size_t)(n0 + srow) * D_ + shalf;

  s16x8 ar[4], br[4];
#pragma unroll
  for (int c = 0; c < 4; ++c) {
    ar[c] = *(const s16x8*)(ap + c * 8);
    br[c] = *(const s16x8*)(bp + c * 8);
  }

  for (int k0 = 0; k0 < D_; k0 += 64) {
    __syncthreads();
#pragma unroll
    for (int c = 0; c < 4; ++c) {
      *(s16x8*)&As[srow][shalf + c * 8] = ar[c];
      *(s16x8*)&Bs[srow][shalf + c * 8] = br[c];
    }
    __syncthreads();
    if (k0 + 64 < D_) {
#pragma unroll
      for (int c = 0; c < 4; ++c) {
        ar[c] = *(const s16x8*)(ap + k0 + 64 + c * 8);
        br[c] = *(const s16x8*)(bp + k0 + 64 + c * 8);
      }
    }
#pragma unroll
    for (int kk = 0; kk < 64; kk += 32) {
      s16x8 af[4], bfr[4];
#pragma unroll
      for (int m = 0; m < 4; ++m)
        af[m] = *(const s16x8*)&As[wr * 64 + m * 16 + l15][kk + g * 8];
#pragma unroll
      for (int n = 0; n < 4; ++n)
        bfr[n] = *(const s16x8*)&Bs[wc * 64 + n * 16 + l15][kk + g * 8];
#pragma unroll
      for (int m = 0; m < 4; ++m)
#pragma unroll
        for (int n = 0; n < 4; ++n)
          acc[m][n] = __builtin_amdgcn_mfma_f32_16x16x32_bf16(af[m], bfr[n], acc[m][n], 0, 0, 0);
    }
  }

#pragma unroll
  for (int m = 0; m < 4; ++m) {
#pragma unroll
    for (int n = 0; n < 4; ++n) {
      const int col = n0 + wc * 64 + n * 16 + l15;
      const float bv = bias[col];
#pragma unroll
      for (int i = 0; i < 4; ++i) {
        const int row = m0 + wr * 64 + m * 16 + g * 4 + i;
        float v = acc[m][n][i] + bv;
        if (MODE == 1) {
          ((float*)outp)[(size_t)row * D_ + col] = v + resid[(size_t)row * D_ + col];
        } else {
          ((short*)outp)[(size_t)row * D_ + col] = f2bs(v * mult);
        }
      }
    }
  }
}

__global__ __launch_bounds__(256) void gemm_qkv_kernel(
    const short* __restrict__ xb, const short* __restrict__ wq,
    const short* __restrict__ wk, const short* __restrict__ wv,
    const float* __restrict__ bq, const float* __restrict__ bk,
    const float* __restrict__ bv, const float* __restrict__ scale_p,
    short* __restrict__ Qb, short* __restrict__ Kb, short* __restrict__ Vb) {
  __shared__ __align__(16) short As[128][72];
  __shared__ __align__(16) short Bs[128][72];
  const short* W;
  const float* bias;
  short* out;
  float mult = 1.0f;
  if (blockIdx.z == 0) { W = wq; bias = bq; out = Qb; mult = scale_p[0] * 1.44269504f; }
  else if (blockIdx.z == 1) { W = wk; bias = bk; out = Kb; }
  else { W = wv; bias = bv; out = Vb; }
  gemm_core<0>(As, Bs, xb, W, bias, nullptr, out, mult);
}

__global__ __launch_bounds__(256) void gemm_out_kernel(
    const short* __restrict__ ctx, const short* __restrict__ wo,
    const float* __restrict__ bo, const float* __restrict__ x,
    float* __restrict__ out) {
  __shared__ __align__(16) short As[128][72];
  __shared__ __align__(16) short Bs[128][72];
  gemm_core<1>(As, Bs, ctx, wo, bo, x, out, 1.0f);
}

// ---------------- fused flash attention: 32x32 MFMA, register P -------------
// r7-green per-wave body VERBATIM. Changes: QBLK 128->256 (4 waves x 64 q,
// w in [0,4), qt in [0,8)); staging kept byte-identical by gating to t<128
// (same role formulas); grid 256 = 8 qt x 32 (h,b); T5 setprio around MFMA
// clusters. Single buffer, 2 barriers/tile (the proven rhythm).
__global__ __launch_bounds__(256) void attn_kernel(
    const short* __restrict__ Qb, const short* __restrict__ Kb,
    const short* __restrict__ Vb, short* __restrict__ ctx) {
  __shared__ __align__(16) short Ks[64][64];     // col ^ ((row&7)<<3)
  __shared__ __align__(16) unsigned Vt[64][36];  // Vt[dh][keypair]

  // XCD-aware swizzle: all 8 q-tiles of one (h,b) on one XCD
  const int bid = blockIdx.x;                // 0..255
  const int xcd = bid & 7, slot = bid >> 3;  // slot 0..31
  const int grp = ((slot >> 3) << 3) | xcd;  // 0..31 = h*2+b
  const int qt = slot & 7;                   // 0..7
  const int h = grp >> 1, b = grp & 1;

  const int hc = h * 64;
  const size_t tokbase = (size_t)b * T_;
  const int t = threadIdx.x, lane = t & 63, w = t >> 6;  // w in [0,4)
  const int l31 = lane & 31, hbit = lane >> 5;
  const int swz = (l31 & 7) << 3;

  // Q fragments in registers: B[k=dh][col=q]  (body verbatim; qt*256 + w*64)
  s16x8 qf[2][4];
#pragma unroll
  for (int qg = 0; qg < 2; ++qg) {
    const short* qp =
        Qb + (tokbase + (size_t)(qt * 256 + w * 64 + qg * 32 + l31)) * D_ + hc + hbit * 8;
#pragma unroll
    for (int ks = 0; ks < 4; ++ks) qf[qg][ks] = *(const s16x8*)(qp + ks * 16);
  }

  // staging roles — VERBATIM r7 formulas on t, active only for t<128
  const int krow = t >> 1, kcolb = (t & 1) * 32, kswz = (krow & 7) << 3;
  const int va = t & 31, vd0 = (t >> 5) * 16;
  const short* kp = Kb + (tokbase + krow) * D_ + hc + kcolb;
  const short* vp = Vb + (tokbase + 2 * (size_t)va) * D_ + hc + vd0;

  // prefetch tile 0 (staging threads only)
  s16x8 kr[4], vA0, vA1, vB0, vB1;
  if (t < 128) {
#pragma unroll
    for (int c = 0; c < 4; ++c) kr[c] = *(const s16x8*)(kp + c * 8);
    vA0 = *(const s16x8*)vp;
    vA1 = *(const s16x8*)(vp + 8);
    vB0 = *(const s16x8*)(vp + D_);
    vB1 = *(const s16x8*)(vp + D_ + 8);
  }

  f32x16 acc[2][2];  // [db][qg]
#pragma unroll
  for (int a = 0; a < 2; ++a)
#pragma unroll
    for (int b2 = 0; b2 < 2; ++b2)
#pragma unroll
      for (int i = 0; i < 16; ++i) acc[a][b2][i] = 0.f;
  float lsum[2] = {0.f, 0.f};

  const int NT = T_ / 64;
  for (int kt = 0; kt < NT; ++kt) {
    __syncthreads();
    if (t < 128) {
      // K -> LDS (4 x b128, chunk-swizzled)  — verbatim
#pragma unroll
      for (int c = 0; c < 4; ++c)
        *(s16x8*)&Ks[krow][(kcolb + c * 8) ^ kswz] = kr[c];
      // V -> LDS transposed pack (16 x b32)  — verbatim
      u32x4 a0 = __builtin_bit_cast(u32x4, vA0), b0 = __builtin_bit_cast(u32x4, vB0);
      u32x4 a1 = __builtin_bit_cast(u32x4, vA1), b1 = __builtin_bit_cast(u32x4, vB1);
#pragma unroll
      for (int jd = 0; jd < 4; ++jd) {
        Vt[vd0 + 2 * jd][va] = __builtin_amdgcn_perm(b0[jd], a0[jd], 0x05040100u);
        Vt[vd0 + 2 * jd + 1][va] = __builtin_amdgcn_perm(b0[jd], a0[jd], 0x07060302u);
        Vt[vd0 + 8 + 2 * jd][va] = __builtin_amdgcn_perm(b1[jd], a1[jd], 0x05040100u);
        Vt[vd0 + 8 + 2 * jd + 1][va] = __builtin_amdgcn_perm(b1[jd], a1[jd], 0x07060302u);
      }
    }
    __syncthreads();
    if (t < 128 && kt + 1 < NT) {  // issue next-tile loads early
      const short* kp2 = kp + (size_t)(kt + 1) * 64 * D_;
#pragma unroll
      for (int c = 0; c < 4; ++c) kr[c] = *(const s16x8*)(kp2 + c * 8);
      const short* vp2 = vp + (size_t)(kt + 1) * 64 * D_;
      vA0 = *(const s16x8*)vp2;
      vA1 = *(const s16x8*)(vp2 + 8);
      vB0 = *(const s16x8*)(vp2 + D_);
      vB1 = *(const s16x8*)(vp2 + D_ + 8);
    }

#pragma unroll
    for (int kb = 0; kb < 2; ++kb) {
      // K fragments: A[row=key][k]  — verbatim
      s16x8 kf[4];
#pragma unroll
      for (int ks = 0; ks < 4; ++ks)
        kf[ks] = *(const s16x8*)&Ks[kb * 32 + l31][(ks * 16 + hbit * 8) ^ swz];
      // S^T = K Q^T
      f32x16 S0, S1;
#pragma unroll
      for (int i = 0; i < 16; ++i) { S0[i] = 0.f; S1[i] = 0.f; }
      __builtin_amdgcn_s_setprio(1);
#pragma unroll
      for (int ks = 0; ks < 4; ++ks) {
        S0 = __builtin_amdgcn_mfma_f32_32x32x16_bf16(kf[ks], qf[0][ks], S0, 0, 0, 0);
        S1 = __builtin_amdgcn_mfma_f32_32x32x16_bf16(kf[ks], qf[1][ks], S1, 0, 0, 0);
      }
      __builtin_amdgcn_s_setprio(0);
      // p = exp2(s); pack to bf16 pairs; build P^T B-frags via lane^32 swap
      s16x8 pf[2][2];  // [qg][s2]
#pragma unroll
      for (int qg = 0; qg < 2; ++qg) {
        const f32x16& S = qg ? S1 : S0;
        unsigned d[8];
        float ls = 0.f;
#pragma unroll
        for (int m = 0; m < 4; ++m) {
          float p0 = __builtin_amdgcn_exp2f(S[4 * m + 0]);
          float p1 = __builtin_amdgcn_exp2f(S[4 * m + 1]);
          float p2 = __builtin_amdgcn_exp2f(S[4 * m + 2]);
          float p3 = __builtin_amdgcn_exp2f(S[4 * m + 3]);
          ls += (p0 + p1) + (p2 + p3);
          d[m * 2 + 0] = cvt_pk_bf16(p0, p1);
          d[m * 2 + 1] = cvt_pk_bf16(p2, p3);
        }
        lsum[qg] += ls;
#pragma unroll
        for (int s2 = 0; s2 < 2; ++s2) {
          unsigned own0 = d[(2 * s2) * 2 + 0], own1 = d[(2 * s2) * 2 + 1];
          unsigned oth0 = d[(2 * s2 + 1) * 2 + 0], oth1 = d[(2 * s2 + 1) * 2 + 1];
          unsigned send0 = hbit ? own0 : oth0;
          unsigned send1 = hbit ? own1 : oth1;
          unsigned r0 = (unsigned)__shfl_xor((int)send0, 32);
          unsigned r1 = (unsigned)__shfl_xor((int)send1, 32);
          u32x4 bf;
          bf[0] = hbit ? r0 : own0;
          bf[1] = hbit ? r1 : own1;
          bf[2] = hbit ? oth0 : r0;
          bf[3] = hbit ? oth1 : r1;
          pf[qg][s2] = __builtin_bit_cast(s16x8, bf);
        }
      }
      // O^T += V^T P^T
      __builtin_amdgcn_s_setprio(1);
#pragma unroll
      for (int db = 0; db < 2; ++db) {
        s16x8 av0 = *(const s16x8*)&Vt[db * 32 + l31][kb * 16 + hbit * 4];
        s16x8 av1 = *(const s16x8*)&Vt[db * 32 + l31][kb * 16 + 8 + hbit * 4];
#pragma unroll
        for (int qg = 0; qg < 2; ++qg) {
          acc[db][qg] = __builtin_amdgcn_mfma_f32_32x32x16_bf16(av0, pf[qg][0], acc[db][qg], 0, 0, 0);
          acc[db][qg] = __builtin_amdgcn_mfma_f32_32x32x16_bf16(av1, pf[qg][1], acc[db][qg], 0, 0, 0);
        }
      }
      __builtin_amdgcn_s_setprio(0);
    }
  }

  // epilogue: O = acc / lsum ; dh = 32db + 8rq + 4hbit + i, q = qg*32+l31
#pragma unroll
  for (int qg = 0; qg < 2; ++qg) {
    lsum[qg] += __shfl_xor(lsum[qg], 32);
    float inv = 1.f / lsum[qg];
    const size_t token = tokbase + (size_t)(qt * 256 + w * 64 + qg * 32 + l31);
    short* cp = ctx + token * D_ + hc;
#pragma unroll
    for (int db = 0; db < 2; ++db) {
#pragma unroll
      for (int rq = 0; rq < 4; ++rq) {
        s16x4 o;
        o.x = f2bs(acc[db][qg][rq * 4 + 0] * inv);
        o.y = f2bs(acc[db][qg][rq * 4 + 1] * inv);
        o.z = f2bs(acc[db][qg][rq * 4 + 2] * inv);
        o.w = f2bs(acc[db][qg][rq * 4 + 3] * inv);
        *(s16x4*)(cp + db * 32 + rq * 8 + hbit * 4) = o;
      }
    }
  }
}

// ---------------- in-place LayerNorm over D=1024 ----------------
__global__ __launch_bounds__(256) void ln_kernel(float* __restrict__ out,
                                                 const float* __restrict__ gamma,
                                                 const float* __restrict__ beta) {
  __shared__ float reds[4], redss[4];
  const size_t row = blockIdx.x;
  float* p = out + row * D_;
  const int t = threadIdx.x;
  float4 v = ((const float4*)p)[t];
  float s = v.x + v.y + v.z + v.w;
  float ss = v.x * v.x + v.y * v.y + v.z * v.z + v.w * v.w;
#pragma unroll
  for (int off = 1; off < 64; off <<= 1) {
    s += __shfl_xor(s, off);
    ss += __shfl_xor(ss, off);
  }
  const int wid = t >> 6, lane = t & 63;
  if (lane == 0) { reds[wid] = s; redss[wid] = ss; }
  __syncthreads();
  float S = reds[0] + reds[1] + reds[2] + reds[3];
  float SS = redss[0] + redss[1] + redss[2] + redss[3];
  const float mean = S * (1.f / D_);
  const float var = SS * (1.f / D_) - mean * mean;
  const float r = rsqrtf(var + 1e-3f);
  float4 gm = ((const float4*)gamma)[t];
  float4 bt = ((const float4*)beta)[t];
  float4 o;
  o.x = (v.x - mean) * r * gm.x + bt.x;
  o.y = (v.y - mean) * r * gm.y + bt.y;
  o.z = (v.z - mean) * r * gm.z + bt.z;
  o.w = (v.w - mean) * r * gm.w + bt.w;
  ((float4*)p)[t] = o;
}

extern "C" void kernel_launch(void* const* d_in, const int* in_sizes, int n_in,
                              void* d_out, int out_size, void* d_ws, size_t ws_size,
                              hipStream_t stream) {
  const float* x = (const float*)d_in[0];
  const float* wq = (const float*)d_in[1];
  const float* bq = (const float*)d_in[2];
  const float* wk = (const float*)d_in[3];
  const float* bk = (const float*)d_in[4];
  const float* wv = (const float*)d_in[5];
  const float* bv = (const float*)d_in[6];
  const float* wo = (const float*)d_in[7];
  const float* bo = (const float*)d_in[8];
  const float* scale = (const float*)d_in[9];
  const float* gamma = (const float*)d_in[10];
  const float* beta = (const float*)d_in[11];
  float* out = (float*)d_out;

  short* xb = (short*)d_ws;                    // M*D bf16
  short* wqt = xb + (size_t)M_ * D_;           // D*D (transposed)
  short* wkt = wqt + (size_t)D_ * D_;
  short* wvt = wkt + (size_t)D_ * D_;
  short* wot = wvt + (size_t)D_ * D_;
  short* Qb = wot + (size_t)D_ * D_;           // M*D
  short* Kb = Qb + (size_t)M_ * D_;
  short* Vb = Kb + (size_t)M_ * D_;
  short* ctx = Vb + (size_t)M_ * D_;

  const int n4x = M_ * D_ / 4;
  cvt_f32_bf16<<<dim3((n4x + 255) / 256), 256, 0, stream>>>(x, xb, n4x);
  cvt_transpose<<<dim3(16, 16, 4), 256, 0, stream>>>(wq, wk, wv, wo, wqt, wkt, wvt, wot);

  gemm_qkv_kernel<<<dim3(D_ / 128, M_ / 128, 3), 256, 0, stream>>>(
      xb, wqt, wkt, wvt, bq, bk, bv, scale, Qb, Kb, Vb);

  attn_kernel<<<dim3(256), 256, 0, stream>>>(Qb, Kb, Vb, ctx);

  gemm_out_kernel<<<dim3(D_ / 128, M_ / 128), 256, 0, stream>>>(ctx, wot, bo, x, out);

  ln_kernel<<<dim3(M_), 256, 0, stream>>>(out, gamma, beta);
}

// Round 15
// 134.432 us; speedup vs baseline: 1.1085x; 1.1085x over previous
//
#include <hip/hip_runtime.h>
#include <hip/hip_bf16.h>

#define B_ 2
#define T_ 2048
#define D_ 1024
#define H_ 16
#define M_ (B_ * T_)  // 4096 tokens

typedef __attribute__((ext_vector_type(4))) float f32x4;
typedef __attribute__((ext_vector_type(16))) float f32x16;
typedef __attribute__((ext_vector_type(8))) short s16x8;
typedef __attribute__((ext_vector_type(4))) short s16x4;
typedef __attribute__((ext_vector_type(4))) unsigned u32x4;

__device__ __forceinline__ short f2bs(float f) {
  unsigned u = __builtin_bit_cast(unsigned, f);
  u += 0x7fffu + ((u >> 16) & 1u);
  return (short)(u >> 16);
}
// v_cvt_pk_bf16_f32: dst.lo = bf16(lo), dst.hi = bf16(hi) (RTNE)
__device__ __forceinline__ unsigned cvt_pk_bf16(float lo, float hi) {
  unsigned r;
  asm("v_cvt_pk_bf16_f32 %0, %1, %2" : "=v"(r) : "v"(lo), "v"(hi));
  return r;
}

// ---------------- fp32 -> bf16 convert (x) ----------------
__global__ __launch_bounds__(256) void cvt_f32_bf16(const float* __restrict__ in,
                                                    short* __restrict__ out, int n4) {
  int i = blockIdx.x * 256 + threadIdx.x;
  if (i < n4) {
    float4 v = ((const float4*)in)[i];
    s16x4 o;
    o.x = f2bs(v.x); o.y = f2bs(v.y); o.z = f2bs(v.z); o.w = f2bs(v.w);
    ((s16x4*)out)[i] = o;
  }
}

// ---------------- fp32 W[k][n] -> bf16 Wt[n][k] (transpose) ----------------
__global__ __launch_bounds__(256) void cvt_transpose(
    const float* __restrict__ w0, const float* __restrict__ w1,
    const float* __restrict__ w2, const float* __restrict__ w3,
    short* __restrict__ o0, short* __restrict__ o1,
    short* __restrict__ o2, short* __restrict__ o3) {
  __shared__ float tile[64][65];
  const float* W; short* Wt;
  if (blockIdx.z == 0) { W = w0; Wt = o0; }
  else if (blockIdx.z == 1) { W = w1; Wt = o1; }
  else if (blockIdx.z == 2) { W = w2; Wt = o2; }
  else { W = w3; Wt = o3; }
  const int k0 = blockIdx.x * 64, n0 = blockIdx.y * 64;
  const int t = threadIdx.x;
  const int c = t & 63, r4 = t >> 6;
#pragma unroll
  for (int i = 0; i < 16; ++i) {
    int row = i * 4 + r4;
    tile[row][c] = W[(size_t)(k0 + row) * D_ + n0 + c];
  }
  __syncthreads();
#pragma unroll
  for (int i = 0; i < 16; ++i) {
    int row = i * 4 + r4;
    Wt[(size_t)(n0 + row) * D_ + k0 + c] = f2bs(tile[c][row]);
  }
}

// ---------------- 128x128 bf16 MFMA GEMM core (BK=64, Wt pre-transposed) ----
// r7-green version (best measured). XCD-chunked block swizzle.
template <int MODE>
__device__ __forceinline__ void gemm_core(short As[128][72], short Bs[128][72],
                                          const short* __restrict__ A,
                                          const short* __restrict__ Wt,
                                          const float* __restrict__ bias,
                                          const float* __restrict__ resid,
                                          void* __restrict__ outp, float mult) {
  const int t = threadIdx.x;
  const int lane = t & 63, wid = t >> 6;
  const int l15 = lane & 15, g = lane >> 4;
  const int wr = wid >> 1, wc = wid & 1;
  const int f = blockIdx.y * 8 + blockIdx.x;       // [0,256)
  const int nf = (f & 7) * 32 + (f >> 3);          // bijective remap
  const int n0 = (nf & 7) * 128;
  const int m0 = (nf >> 3) * 128;

  const f32x4 fz = {0.f, 0.f, 0.f, 0.f};
  f32x4 acc[4][4];
#pragma unroll
  for (int m = 0; m < 4; ++m)
#pragma unroll
    for (int n = 0; n < 4; ++n) acc[m][n] = fz;

  const int srow = t >> 1, shalf = (t & 1) * 32;
  const short* ap = A + (size_t)(m0 + srow) * D_ + shalf;
  const short* bp = Wt + (size_t)(n0 + srow) * D_ + shalf;

  s16x8 ar[4], br[4];
#pragma unroll
  for (int c = 0; c < 4; ++c) {
    ar[c] = *(const s16x8*)(ap + c * 8);
    br[c] = *(const s16x8*)(bp + c * 8);
  }

  for (int k0 = 0; k0 < D_; k0 += 64) {
    __syncthreads();
#pragma unroll
    for (int c = 0; c < 4; ++c) {
      *(s16x8*)&As[srow][shalf + c * 8] = ar[c];
      *(s16x8*)&Bs[srow][shalf + c * 8] = br[c];
    }
    __syncthreads();
    if (k0 + 64 < D_) {
#pragma unroll
      for (int c = 0; c < 4; ++c) {
        ar[c] = *(const s16x8*)(ap + k0 + 64 + c * 8);
        br[c] = *(const s16x8*)(bp + k0 + 64 + c * 8);
      }
    }
#pragma unroll
    for (int kk = 0; kk < 64; kk += 32) {
      s16x8 af[4], bfr[4];
#pragma unroll
      for (int m = 0; m < 4; ++m)
        af[m] = *(const s16x8*)&As[wr * 64 + m * 16 + l15][kk + g * 8];
#pragma unroll
      for (int n = 0; n < 4; ++n)
        bfr[n] = *(const s16x8*)&Bs[wc * 64 + n * 16 + l15][kk + g * 8];
#pragma unroll
      for (int m = 0; m < 4; ++m)
#pragma unroll
        for (int n = 0; n < 4; ++n)
          acc[m][n] = __builtin_amdgcn_mfma_f32_16x16x32_bf16(af[m], bfr[n], acc[m][n], 0, 0, 0);
    }
  }

#pragma unroll
  for (int m = 0; m < 4; ++m) {
#pragma unroll
    for (int n = 0; n < 4; ++n) {
      const int col = n0 + wc * 64 + n * 16 + l15;
      const float bv = bias[col];
#pragma unroll
      for (int i = 0; i < 4; ++i) {
        const int row = m0 + wr * 64 + m * 16 + g * 4 + i;
        float v = acc[m][n][i] + bv;
        if (MODE == 1) {
          ((float*)outp)[(size_t)row * D_ + col] = v + resid[(size_t)row * D_ + col];
        } else {
          ((short*)outp)[(size_t)row * D_ + col] = f2bs(v * mult);
        }
      }
    }
  }
}

__global__ __launch_bounds__(256) void gemm_qkv_kernel(
    const short* __restrict__ xb, const short* __restrict__ wq,
    const short* __restrict__ wk, const short* __restrict__ wv,
    const float* __restrict__ bq, const float* __restrict__ bk,
    const float* __restrict__ bv, const float* __restrict__ scale_p,
    short* __restrict__ Qb, short* __restrict__ Kb, short* __restrict__ Vb) {
  __shared__ __align__(16) short As[128][72];
  __shared__ __align__(16) short Bs[128][72];
  const short* W;
  const float* bias;
  short* out;
  float mult = 1.0f;
  if (blockIdx.z == 0) { W = wq; bias = bq; out = Qb; mult = scale_p[0] * 1.44269504f; }
  else if (blockIdx.z == 1) { W = wk; bias = bk; out = Kb; }
  else { W = wv; bias = bv; out = Vb; }
  gemm_core<0>(As, Bs, xb, W, bias, nullptr, out, mult);
}

__global__ __launch_bounds__(256) void gemm_out_kernel(
    const short* __restrict__ ctx, const short* __restrict__ wo,
    const float* __restrict__ bo, const float* __restrict__ x,
    float* __restrict__ out) {
  __shared__ __align__(16) short As[128][72];
  __shared__ __align__(16) short Bs[128][72];
  gemm_core<1>(As, Bs, ctx, wo, bo, x, out, 1.0f);
}

// ---------------- fused flash attention: 32x32 MFMA, register P -------------
// VERBATIM r7-green kernel (passed full harness, 77.5 us, absmax 0.0586).
// FROZEN: r5/r6/r8/r10/r11/r12/r13/r14 showed this module is codegen/timing
// sensitive; this exact build context is the proven one.
// QK^T: S^T[key][q] = mfma32(A=K, B=Q); lane: q=lane&31, key=(r&3)+8(r>>2)+4h.
// PV: O^T[dh][q] = mfma32(A=V^T, B=P^T); P-frag in-register via cvt_pk +
// shfl_xor(32). LDS only for K (XOR-swizzled) and Vt.
__global__ __launch_bounds__(128) void attn_kernel(
    const short* __restrict__ Qb, const short* __restrict__ Kb,
    const short* __restrict__ Vb, short* __restrict__ ctx) {
  __shared__ __align__(16) short Ks[64][64];     // col ^ ((row&7)<<3)
  __shared__ __align__(16) unsigned Vt[64][36];  // Vt[dh][keypair]

  // XCD-aware swizzle: all 16 q-tiles of one (h,b) on one XCD
  const int bid = blockIdx.x;          // 0..511
  const int xcd = bid & 7, slot = bid >> 3;
  const int grp = ((slot >> 4) << 3) | xcd;  // 0..31 = h*2+b
  const int qt = slot & 15;
  const int h = grp >> 1, b = grp & 1;

  const int hc = h * 64;
  const size_t tokbase = (size_t)b * T_;
  const int t = threadIdx.x, lane = t & 63, w = t >> 6;
  const int l31 = lane & 31, hbit = lane >> 5;
  const int swz = (l31 & 7) << 3;

  // Q fragments in registers: B[k=dh][col=q]
  s16x8 qf[2][4];
#pragma unroll
  for (int qg = 0; qg < 2; ++qg) {
    const short* qp =
        Qb + (tokbase + (size_t)(qt * 128 + w * 64 + qg * 32 + l31)) * D_ + hc + hbit * 8;
#pragma unroll
    for (int ks = 0; ks < 4; ++ks) qf[qg][ks] = *(const s16x8*)(qp + ks * 16);
  }

  // staging roles (128 threads)
  const int krow = t >> 1, kcolb = (t & 1) * 32, kswz = (krow & 7) << 3;
  const int va = t & 31, vd0 = (t >> 5) * 16;
  const short* kp = Kb + (tokbase + krow) * D_ + hc + kcolb;
  const short* vp = Vb + (tokbase + 2 * (size_t)va) * D_ + hc + vd0;

  // prefetch tile 0
  s16x8 kr[4], vA0, vA1, vB0, vB1;
#pragma unroll
  for (int c = 0; c < 4; ++c) kr[c] = *(const s16x8*)(kp + c * 8);
  vA0 = *(const s16x8*)vp;
  vA1 = *(const s16x8*)(vp + 8);
  vB0 = *(const s16x8*)(vp + D_);
  vB1 = *(const s16x8*)(vp + D_ + 8);

  f32x16 acc[2][2];  // [db][qg]
#pragma unroll
  for (int a = 0; a < 2; ++a)
#pragma unroll
    for (int b2 = 0; b2 < 2; ++b2)
#pragma unroll
      for (int i = 0; i < 16; ++i) acc[a][b2][i] = 0.f;
  float lsum[2] = {0.f, 0.f};

  const int NT = T_ / 64;
  for (int kt = 0; kt < NT; ++kt) {
    __syncthreads();
    // K -> LDS (4 x b128, chunk-swizzled)
#pragma unroll
    for (int c = 0; c < 4; ++c)
      *(s16x8*)&Ks[krow][(kcolb + c * 8) ^ kswz] = kr[c];
    // V -> LDS transposed pack (16 x b32, conflict-free)
    {
      u32x4 a0 = __builtin_bit_cast(u32x4, vA0), b0 = __builtin_bit_cast(u32x4, vB0);
      u32x4 a1 = __builtin_bit_cast(u32x4, vA1), b1 = __builtin_bit_cast(u32x4, vB1);
#pragma unroll
      for (int jd = 0; jd < 4; ++jd) {
        Vt[vd0 + 2 * jd][va] = __builtin_amdgcn_perm(b0[jd], a0[jd], 0x05040100u);
        Vt[vd0 + 2 * jd + 1][va] = __builtin_amdgcn_perm(b0[jd], a0[jd], 0x07060302u);
        Vt[vd0 + 8 + 2 * jd][va] = __builtin_amdgcn_perm(b1[jd], a1[jd], 0x05040100u);
        Vt[vd0 + 8 + 2 * jd + 1][va] = __builtin_amdgcn_perm(b1[jd], a1[jd], 0x07060302u);
      }
    }
    __syncthreads();
    if (kt + 1 < NT) {  // issue next-tile loads early; hide under compute
      const short* kp2 = kp + (size_t)(kt + 1) * 64 * D_;
#pragma unroll
      for (int c = 0; c < 4; ++c) kr[c] = *(const s16x8*)(kp2 + c * 8);
      const short* vp2 = vp + (size_t)(kt + 1) * 64 * D_;
      vA0 = *(const s16x8*)vp2;
      vA1 = *(const s16x8*)(vp2 + 8);
      vB0 = *(const s16x8*)(vp2 + D_);
      vB1 = *(const s16x8*)(vp2 + D_ + 8);
    }

#pragma unroll
    for (int kb = 0; kb < 2; ++kb) {
      // K fragments: A[row=key][k]
      s16x8 kf[4];
#pragma unroll
      for (int ks = 0; ks < 4; ++ks)
        kf[ks] = *(const s16x8*)&Ks[kb * 32 + l31][(ks * 16 + hbit * 8) ^ swz];
      // S^T = K Q^T
      f32x16 S0, S1;
#pragma unroll
      for (int i = 0; i < 16; ++i) { S0[i] = 0.f; S1[i] = 0.f; }
#pragma unroll
      for (int ks = 0; ks < 4; ++ks) {
        S0 = __builtin_amdgcn_mfma_f32_32x32x16_bf16(kf[ks], qf[0][ks], S0, 0, 0, 0);
        S1 = __builtin_amdgcn_mfma_f32_32x32x16_bf16(kf[ks], qf[1][ks], S1, 0, 0, 0);
      }
      // p = exp2(s); pack to bf16 pairs; build P^T B-frags via lane^32 swap
      s16x8 pf[2][2];  // [qg][s2]
#pragma unroll
      for (int qg = 0; qg < 2; ++qg) {
        const f32x16& S = qg ? S1 : S0;
        unsigned d[8];
        float ls = 0.f;
#pragma unroll
        for (int m = 0; m < 4; ++m) {
          float p0 = __builtin_amdgcn_exp2f(S[4 * m + 0]);
          float p1 = __builtin_amdgcn_exp2f(S[4 * m + 1]);
          float p2 = __builtin_amdgcn_exp2f(S[4 * m + 2]);
          float p3 = __builtin_amdgcn_exp2f(S[4 * m + 3]);
          ls += (p0 + p1) + (p2 + p3);
          d[m * 2 + 0] = cvt_pk_bf16(p0, p1);
          d[m * 2 + 1] = cvt_pk_bf16(p2, p3);
        }
        lsum[qg] += ls;
#pragma unroll
        for (int s2 = 0; s2 < 2; ++s2) {
          unsigned own0 = d[(2 * s2) * 2 + 0], own1 = d[(2 * s2) * 2 + 1];
          unsigned oth0 = d[(2 * s2 + 1) * 2 + 0], oth1 = d[(2 * s2 + 1) * 2 + 1];
          unsigned send0 = hbit ? own0 : oth0;
          unsigned send1 = hbit ? own1 : oth1;
          unsigned r0 = (unsigned)__shfl_xor((int)send0, 32);
          unsigned r1 = (unsigned)__shfl_xor((int)send1, 32);
          u32x4 bf;
          bf[0] = hbit ? r0 : own0;
          bf[1] = hbit ? r1 : own1;
          bf[2] = hbit ? oth0 : r0;
          bf[3] = hbit ? oth1 : r1;
          pf[qg][s2] = __builtin_bit_cast(s16x8, bf);
        }
      }
      // O^T += V^T P^T
#pragma unroll
      for (int db = 0; db < 2; ++db) {
        s16x8 av0 = *(const s16x8*)&Vt[db * 32 + l31][kb * 16 + hbit * 4];
        s16x8 av1 = *(const s16x8*)&Vt[db * 32 + l31][kb * 16 + 8 + hbit * 4];
#pragma unroll
        for (int qg = 0; qg < 2; ++qg) {
          acc[db][qg] = __builtin_amdgcn_mfma_f32_32x32x16_bf16(av0, pf[qg][0], acc[db][qg], 0, 0, 0);
          acc[db][qg] = __builtin_amdgcn_mfma_f32_32x32x16_bf16(av1, pf[qg][1], acc[db][qg], 0, 0, 0);
        }
      }
    }
  }

  // epilogue: O = acc / lsum ; dh = 32db + 8rq + 4hbit + i, q = qg*32+l31
#pragma unroll
  for (int qg = 0; qg < 2; ++qg) {
    lsum[qg] += __shfl_xor(lsum[qg], 32);
    float inv = 1.f / lsum[qg];
    const size_t token = tokbase + (size_t)(qt * 128 + w * 64 + qg * 32 + l31);
    short* cp = ctx + token * D_ + hc;
#pragma unroll
    for (int db = 0; db < 2; ++db) {
#pragma unroll
      for (int rq = 0; rq < 4; ++rq) {
        s16x4 o;
        o.x = f2bs(acc[db][qg][rq * 4 + 0] * inv);
        o.y = f2bs(acc[db][qg][rq * 4 + 1] * inv);
        o.z = f2bs(acc[db][qg][rq * 4 + 2] * inv);
        o.w = f2bs(acc[db][qg][rq * 4 + 3] * inv);
        *(s16x4*)(cp + db * 32 + rq * 8 + hbit * 4) = o;
      }
    }
  }
}

// ---------------- in-place LayerNorm over D=1024 ----------------
__global__ __launch_bounds__(256) void ln_kernel(float* __restrict__ out,
                                                 const float* __restrict__ gamma,
                                                 const float* __restrict__ beta) {
  __shared__ float reds[4], redss[4];
  const size_t row = blockIdx.x;
  float* p = out + row * D_;
  const int t = threadIdx.x;
  float4 v = ((const float4*)p)[t];
  float s = v.x + v.y + v.z + v.w;
  float ss = v.x * v.x + v.y * v.y + v.z * v.z + v.w * v.w;
#pragma unroll
  for (int off = 1; off < 64; off <<= 1) {
    s += __shfl_xor(s, off);
    ss += __shfl_xor(ss, off);
  }
  const int wid = t >> 6, lane = t & 63;
  if (lane == 0) { reds[wid] = s; redss[wid] = ss; }
  __syncthreads();
  float S = reds[0] + reds[1] + reds[2] + reds[3];
  float SS = redss[0] + redss[1] + redss[2] + redss[3];
  const float mean = S * (1.f / D_);
  const float var = SS * (1.f / D_) - mean * mean;
  const float r = rsqrtf(var + 1e-3f);
  float4 gm = ((const float4*)gamma)[t];
  float4 bt = ((const float4*)beta)[t];
  float4 o;
  o.x = (v.x - mean) * r * gm.x + bt.x;
  o.y = (v.y - mean) * r * gm.y + bt.y;
  o.z = (v.z - mean) * r * gm.z + bt.z;
  o.w = (v.w - mean) * r * gm.w + bt.w;
  ((float4*)p)[t] = o;
}

extern "C" void kernel_launch(void* const* d_in, const int* in_sizes, int n_in,
                              void* d_out, int out_size, void* d_ws, size_t ws_size,
                              hipStream_t stream) {
  const float* x = (const float*)d_in[0];
  const float* wq = (const float*)d_in[1];
  const float* bq = (const float*)d_in[2];
  const float* wk = (const float*)d_in[3];
  const float* bk = (const float*)d_in[4];
  const float* wv = (const float*)d_in[5];
  const float* bv = (const float*)d_in[6];
  const float* wo = (const float*)d_in[7];
  const float* bo = (const float*)d_in[8];
  const float* scale = (const float*)d_in[9];
  const float* gamma = (const float*)d_in[10];
  const float* beta = (const float*)d_in[11];
  float* out = (float*)d_out;

  short* xb = (short*)d_ws;                    // M*D bf16
  short* wqt = xb + (size_t)M_ * D_;           // D*D (transposed)
  short* wkt = wqt + (size_t)D_ * D_;
  short* wvt = wkt + (size_t)D_ * D_;
  short* wot = wvt + (size_t)D_ * D_;
  short* Qb = wot + (size_t)D_ * D_;           // M*D
  short* Kb = Qb + (size_t)M_ * D_;
  short* Vb = Kb + (size_t)M_ * D_;
  short* ctx = Vb + (size_t)M_ * D_;

  const int n4x = M_ * D_ / 4;
  cvt_f32_bf16<<<dim3((n4x + 255) / 256), 256, 0, stream>>>(x, xb, n4x);
  cvt_transpose<<<dim3(16, 16, 4), 256, 0, stream>>>(wq, wk, wv, wo, wqt, wkt, wvt, wot);

  gemm_qkv_kernel<<<dim3(D_ / 128, M_ / 128, 3), 256, 0, stream>>>(
      xb, wqt, wkt, wvt, bq, bk, bv, scale, Qb, Kb, Vb);

  attn_kernel<<<dim3(512), 128, 0, stream>>>(Qb, Kb, Vb, ctx);

  gemm_out_kernel<<<dim3(D_ / 128, M_ / 128), 256, 0, stream>>>(ctx, wot, bo, x, out);

  ln_kernel<<<dim3(M_), 256, 0, stream>>>(out, gamma, beta);
}